// Round 5
// baseline (555.752 us; speedup 1.0000x reference)
//
#include <hip/hip_runtime.h>
#include <math.h>

#define BB 32
#define CC 3
#define HH 224
#define WW 224
#define HWS (HH*WW)            // 50176
#define NPIX (BB*HWS)          // 1,605,632
#define NTAPS (9*HWS)          // 451,584
#define EPS_IN 1e-5f
#define LNUM 10

// 2D tile: 16 rows x 32 cols per block (2 px/thread), halo RAD=4.
// RAD=4 covers |offset| <= 3 (P ~ 2e-9 per tap); the cold fixup loop handles
// anything larger, so correctness never depends on RAD.
#define TR 16
#define TC 32
#define RAD 4
#define WROWS (TR + 2*RAD)         // 24
#define WCOLS (TC + 2*RAD)         // 40
#define WSTRIDE 40                 // row stride (float4 cells)
#define WCELLS (WROWS * WCOLS)     // 960
#define NTILE ((HH/TR) * (WW/TC))  // 14*7 = 98
#define NBLK (NTILE * BB)          // 3136

__device__ __forceinline__ float fast_tanh(float z) {
    z = fminf(fmaxf(z, -15.f), 15.f);
    float e = __expf(2.f * z);
    return (e - 1.f) * __frcp_rn(e + 1.f);
}

__global__ void zero_kernel(float* __restrict__ p, int n) {
    int i = blockIdx.x * 256 + threadIdx.x;
    if (i < n) p[i] = 0.f;
}

// ------- precompute per-tap: border-masked bilinear weights (float4) and
// corner coords packed as 2 x short (int). Layer-invariant, hoisted out of
// the 10x conv loop.
__global__ __launch_bounds__(256) void taps_kernel(
    const float* __restrict__ off,   // [18,H,W] batch-0 offset plane
    float4* __restrict__ tw,         // [9,HW] weights (border-masked)
    int*    __restrict__ tc)         // [9,HW] packed (ix0<<16)|(iy0&0xffff)
{
    int gid = blockIdx.x * 256 + threadIdx.x;    // k*HWS + pix, grid exact
    int k = gid / HWS, pix = gid - k * HWS;
    int h = pix / WW, wc = pix - h * WW;
    int ky = k / 3, kx = k - 3 * ky;
    float dy = off[(2 * k)     * HWS + pix];
    float dx = off[(2 * k + 1) * HWS + pix];
    float py = (float)(h  + ky - 1) + dy;
    float px = (float)(wc + kx - 1) + dx;
    float y0f = floorf(py), x0f = floorf(px);
    float fy = py - y0f, fx = px - x0f;
    int iy0 = (int)y0f, ix0 = (int)x0f;
    int iy1 = iy0 + 1,  ix1 = ix0 + 1;
    float vy0 = (iy0 >= 0 && iy0 < HH) ? 1.f : 0.f;
    float vy1 = (iy1 >= 0 && iy1 < HH) ? 1.f : 0.f;
    float vx0 = (ix0 >= 0 && ix0 < WW) ? 1.f : 0.f;
    float vx1 = (ix1 >= 0 && ix1 < WW) ? 1.f : 0.f;
    float4 w;
    w.x = (1.f - fy) * (1.f - fx) * vy0 * vx0;
    w.y = (1.f - fy) * fx         * vy0 * vx1;
    w.z = fy         * (1.f - fx) * vy1 * vx0;
    w.w = fy         * fx         * vy1 * vx1;
    tw[gid] = w;
    int cy = min(max(iy0, -30000), 30000);
    int cx = min(max(ix0, -30000), 30000);
    tc[gid] = (cx << 16) | (cy & 0xffff);
}

__global__ __launch_bounds__(256) void pack_kernel(
    const float* __restrict__ x, float4* __restrict__ xi)
{
    int g = blockIdx.x * 256 + threadIdx.x;
    int b = g / HWS, pix = g - b * HWS;
    const float* xb = x + (size_t)b * (CC * HWS) + pix;
    xi[g] = make_float4(xb[0], xb[HWS], xb[2 * HWS], 0.f);
}

// R5: 2 px/thread (rows ry, ry+8 of a 16x32 tile). Two independent
// LDS-load->FMA chains per k-iteration keep the CU LDS unit fed (R4
// post-mortem: conv ran 2.5x above the ~20us LDS-issue floor because each
// tap's 4 ds_read_b128 were followed by dependent FMAs with only 12
// waves/CU to hide ~120cyc LDS latency). Staging redundancy 2.5 -> 1.875
// cells/pixel; per-wave fixed costs amortized over 2x output.
template<int DO_NORM>
__global__ __launch_bounds__(256, 3) void conv_fused(
    const float4* __restrict__ xi,       // prev RAW activations [B*HWS]
    const float4* __restrict__ tw,       // [9,HW] masked bilinear weights
    const int*    __restrict__ tc,       // [9,HW] packed corner coords
    const float*  __restrict__ wt,       // [3,3,9]
    const float*  __restrict__ stats_in, // [B*3][2] prev layer
    const float*  __restrict__ gamma,
    const float*  __restrict__ beta,
    float4* __restrict__ yo,             // RAW conv out [B*HWS]
    float* __restrict__ stats_out)       // [B*3][2] this layer
{
    __shared__ float4 win[WROWS * WSTRIDE];
    __shared__ float  w_s[81];
    __shared__ float  red[4][6];

    int t = threadIdx.x;
    if (t < 81) w_s[t] = wt[t];

    int p = blockIdx.x;
    int logical = (p & 7) * (NBLK / 8) + (p >> 3);
    int b    = logical & 31;
    int tile = logical >> 5;             // 0..97
    int ty = tile / 7, tx = tile - ty * 7;
    int by0 = ty * TR, bx0 = tx * TC;
    int wly = by0 - RAD, wlx = bx0 - RAD;

    const float4* xb = xi + (size_t)b * HWS;

    int ry = t >> 5, rx = t & 31;        // ry 0..7
    int pixA = (by0 + ry) * WW + (bx0 + rx);
    int pixB = pixA + 8 * WW;            // rows ry and ry+8

    // hoist packed corner coords for both pixels (independent load streams)
    int tckA[9], tckB[9];
    #pragma unroll
    for (int k = 0; k < 9; ++k) {
        tckA[k] = tc[k * HWS + pixA];
        tckB[k] = tc[k * HWS + pixB];
    }

    // uniform per-(b,c) norm params of the PREVIOUS layer (staging only)
    float mean0=0.f, mean1=0.f, mean2=0.f;
    float g0=1.f, g1=1.f, g2=1.f, bt0=0.f, bt1=0.f, bt2=0.f;
    if (DO_NORM) {
        const float* st = stats_in + b * 6;
        mean0 = st[0] * (1.f/HWS); mean1 = st[2] * (1.f/HWS); mean2 = st[4] * (1.f/HWS);
        float v0 = fmaxf(st[1]*(1.f/HWS) - mean0*mean0, 0.f);
        float v1 = fmaxf(st[3]*(1.f/HWS) - mean1*mean1, 0.f);
        float v2 = fmaxf(st[5]*(1.f/HWS) - mean2*mean2, 0.f);
        g0 = gamma[0] * rsqrtf(v0 + EPS_IN); bt0 = beta[0];
        g1 = gamma[1] * rsqrtf(v1 + EPS_IN); bt1 = beta[1];
        g2 = gamma[2] * rsqrtf(v2 + EPS_IN); bt2 = beta[2];
    }

    // ---- stage window (norm+tanh of prev layer applied on the fly) ----
    #pragma unroll
    for (int i = 0; i < 4; ++i) {
        int cell = t + i * 256;
        if (cell < WCELLS) {
            int wy = cell / WCOLS, wx = cell - wy * WCOLS;
            int gy = min(max(wly + wy, 0), HH - 1);   // clamp: value only used
            int gx = min(max(wlx + wx, 0), WW - 1);   // when weight != 0
            float4 v = xb[gy * WW + gx];
            if (DO_NORM) {
                v.x = fast_tanh((v.x - mean0) * g0 + bt0);
                v.y = fast_tanh((v.y - mean1) * g1 + bt1);
                v.z = fast_tanh((v.z - mean2) * g2 + bt2);
            }
            win[wy * WSTRIDE + wx] = v;
        }
    }
    __syncthreads();

    float a0A = 0.f, a1A = 0.f, a2A = 0.f;
    float a0B = 0.f, a1B = 0.f, a2B = 0.f;
    unsigned badA = 0u, badB = 0u;

    #pragma unroll
    for (int k = 0; k < 9; ++k) {
        // ---- pixel A ----
        int pcA  = tckA[k];
        int iyA = (int)(short)(pcA & 0xffff);
        int ixA = pcA >> 16;
        int cyA = iyA - wly, cxA = ixA - wlx;
        bool inwA = ((unsigned)cyA <= (unsigned)(WROWS - 2)) &
                    ((unsigned)cxA <= (unsigned)(WCOLS - 2));
        float mA = inwA ? 1.f : 0.f;
        badA |= (inwA ? 0u : 1u) << k;
        float4 wA = tw[k * HWS + pixA];
        wA.x *= mA; wA.y *= mA; wA.z *= mA; wA.w *= mA;
        int baseA = min(max(cyA, 0), WROWS - 2) * WSTRIDE
                  + min(max(cxA, 0), WCOLS - 2);

        // ---- pixel B ----
        int pcB  = tckB[k];
        int iyB = (int)(short)(pcB & 0xffff);
        int ixB = pcB >> 16;
        int cyB = iyB - wly, cxB = ixB - wlx;
        bool inwB = ((unsigned)cyB <= (unsigned)(WROWS - 2)) &
                    ((unsigned)cxB <= (unsigned)(WCOLS - 2));
        float mB = inwB ? 1.f : 0.f;
        badB |= (inwB ? 0u : 1u) << k;
        float4 wB = tw[k * HWS + pixB];
        wB.x *= mB; wB.y *= mB; wB.z *= mB; wB.w *= mB;
        int baseB = min(max(cyB, 0), WROWS - 2) * WSTRIDE
                  + min(max(cxB, 0), WCOLS - 2);

        // two independent LDS read chains
        float4 vA = win[baseA];
        float4 vB = win[baseB];
        float s0A = vA.x * wA.x, s1A = vA.y * wA.x, s2A = vA.z * wA.x;
        float s0B = vB.x * wB.x, s1B = vB.y * wB.x, s2B = vB.z * wB.x;
        vA = win[baseA + 1];
        vB = win[baseB + 1];
        s0A = fmaf(vA.x, wA.y, s0A); s1A = fmaf(vA.y, wA.y, s1A); s2A = fmaf(vA.z, wA.y, s2A);
        s0B = fmaf(vB.x, wB.y, s0B); s1B = fmaf(vB.y, wB.y, s1B); s2B = fmaf(vB.z, wB.y, s2B);
        vA = win[baseA + WSTRIDE];
        vB = win[baseB + WSTRIDE];
        s0A = fmaf(vA.x, wA.z, s0A); s1A = fmaf(vA.y, wA.z, s1A); s2A = fmaf(vA.z, wA.z, s2A);
        s0B = fmaf(vB.x, wB.z, s0B); s1B = fmaf(vB.y, wB.z, s1B); s2B = fmaf(vB.z, wB.z, s2B);
        vA = win[baseA + WSTRIDE + 1];
        vB = win[baseB + WSTRIDE + 1];
        s0A = fmaf(vA.x, wA.w, s0A); s1A = fmaf(vA.y, wA.w, s1A); s2A = fmaf(vA.z, wA.w, s2A);
        s0B = fmaf(vB.x, wB.w, s0B); s1B = fmaf(vB.y, wB.w, s1B); s2B = fmaf(vB.z, wB.w, s2B);

        a0A = fmaf(s2A, w_s[18 + k], fmaf(s1A, w_s[ 9 + k], fmaf(s0A, w_s[     k], a0A)));
        a1A = fmaf(s2A, w_s[45 + k], fmaf(s1A, w_s[36 + k], fmaf(s0A, w_s[27 + k], a1A)));
        a2A = fmaf(s2A, w_s[72 + k], fmaf(s1A, w_s[63 + k], fmaf(s0A, w_s[54 + k], a2A)));
        a0B = fmaf(s2B, w_s[18 + k], fmaf(s1B, w_s[ 9 + k], fmaf(s0B, w_s[27 + k - 27], a0B)));
        a1B = fmaf(s2B, w_s[45 + k], fmaf(s1B, w_s[36 + k], fmaf(s0B, w_s[27 + k], a1B)));
        a2B = fmaf(s2B, w_s[72 + k], fmaf(s1B, w_s[63 + k], fmaf(s0B, w_s[54 + k], a2B)));
    }

    // ---- COLD fixup: taps outside the halo (|offset| > 3), essentially never ----
    if (__builtin_expect((badA | badB) != 0u, 0)) {
        auto fix = [&](unsigned bad, int pixq,
                       float& f0, float& f1, float& f2) {
            while (bad) {
                int k = __ffs(bad) - 1; bad &= bad - 1;
                int pc  = tc[k * HWS + pixq];
                int iy0 = (int)(short)(pc & 0xffff);
                int ix0 = pc >> 16;
                float4 w = tw[k * HWS + pixq];   // already border-masked
                int cy0 = min(max(iy0, 0), HH - 1), cy1 = min(max(iy0 + 1, 0), HH - 1);
                int cx0 = min(max(ix0, 0), WW - 1), cx1 = min(max(ix0 + 1, 0), WW - 1);
                float s0, s1, s2;
                float4 v = xb[cy0 * WW + cx0];
                if (DO_NORM) { v.x = fast_tanh((v.x-mean0)*g0+bt0); v.y = fast_tanh((v.y-mean1)*g1+bt1); v.z = fast_tanh((v.z-mean2)*g2+bt2); }
                s0 = v.x * w.x; s1 = v.y * w.x; s2 = v.z * w.x;
                v = xb[cy0 * WW + cx1];
                if (DO_NORM) { v.x = fast_tanh((v.x-mean0)*g0+bt0); v.y = fast_tanh((v.y-mean1)*g1+bt1); v.z = fast_tanh((v.z-mean2)*g2+bt2); }
                s0 = fmaf(v.x, w.y, s0); s1 = fmaf(v.y, w.y, s1); s2 = fmaf(v.z, w.y, s2);
                v = xb[cy1 * WW + cx0];
                if (DO_NORM) { v.x = fast_tanh((v.x-mean0)*g0+bt0); v.y = fast_tanh((v.y-mean1)*g1+bt1); v.z = fast_tanh((v.z-mean2)*g2+bt2); }
                s0 = fmaf(v.x, w.z, s0); s1 = fmaf(v.y, w.z, s1); s2 = fmaf(v.z, w.z, s2);
                v = xb[cy1 * WW + cx1];
                if (DO_NORM) { v.x = fast_tanh((v.x-mean0)*g0+bt0); v.y = fast_tanh((v.y-mean1)*g1+bt1); v.z = fast_tanh((v.z-mean2)*g2+bt2); }
                s0 = fmaf(v.x, w.w, s0); s1 = fmaf(v.y, w.w, s1); s2 = fmaf(v.z, w.w, s2);
                f0 = fmaf(s2, w_s[18 + k], fmaf(s1, w_s[ 9 + k], fmaf(s0, w_s[     k], f0)));
                f1 = fmaf(s2, w_s[45 + k], fmaf(s1, w_s[36 + k], fmaf(s0, w_s[27 + k], f1)));
                f2 = fmaf(s2, w_s[72 + k], fmaf(s1, w_s[63 + k], fmaf(s0, w_s[54 + k], f2)));
            }
        };
        fix(badA, pixA, a0A, a1A, a2A);
        fix(badB, pixB, a0B, a1B, a2B);
    }

    yo[(size_t)b * HWS + pixA] = make_float4(a0A, a1A, a2A, 0.f);
    yo[(size_t)b * HWS + pixB] = make_float4(a0B, a1B, a2B, 0.f);

    // ---- per-(b,channel) sum / sumsq reduction (both pixels) ----
    float s0r = a0A + a0B, q0 = a0A * a0A + a0B * a0B;
    float s1r = a1A + a1B, q1 = a1A * a1A + a1B * a1B;
    float s2r = a2A + a2B, q2 = a2A * a2A + a2B * a2B;
    #pragma unroll
    for (int o = 32; o > 0; o >>= 1) {
        s0r += __shfl_down(s0r, o); q0 += __shfl_down(q0, o);
        s1r += __shfl_down(s1r, o); q1 += __shfl_down(q1, o);
        s2r += __shfl_down(s2r, o); q2 += __shfl_down(q2, o);
    }
    int wave = t >> 6, lane = t & 63;
    if (lane == 0) {
        red[wave][0] = s0r; red[wave][1] = q0;
        red[wave][2] = s1r; red[wave][3] = q1;
        red[wave][4] = s2r; red[wave][5] = q2;
    }
    __syncthreads();
    if (t < 6) {
        float v = red[0][t] + red[1][t] + red[2][t] + red[3][t];
        int ch = t >> 1, which = t & 1;
        atomicAdd(&stats_out[(b * 3 + ch) * 2 + which], v);
    }
}

__global__ __launch_bounds__(256) void norm_final(
    const float4* __restrict__ y, float* __restrict__ outp,
    const float* __restrict__ stats,
    const float* __restrict__ gamma, const float* __restrict__ beta)
{
    int q = blockIdx.x;
    int logical = (q & 7) * ((NPIX/256) / 8) + (q >> 3);
    int b     = logical & 31;
    int chunk = logical >> 5;
    int pix   = chunk * 256 + threadIdx.x;

    float4 v = y[b * HWS + pix];
    float vin[3] = {v.x, v.y, v.z};
    float r[3];
    #pragma unroll
    for (int c = 0; c < 3; ++c) {
        float s  = stats[(b * 3 + c) * 2 + 0];
        float qq = stats[(b * 3 + c) * 2 + 1];
        float mean = s * (1.f / HWS);
        float var  = fmaxf(qq * (1.f / HWS) - mean * mean, 0.f);
        float gsc  = gamma[c] * rsqrtf(var + EPS_IN);
        r[c] = fast_tanh((vin[c] - mean) * gsc + beta[c]);
    }
    float* ob = outp + (size_t)b * (CC * HWS) + pix;
    ob[0]       = r[0];
    ob[HWS]     = r[1];
    ob[2 * HWS] = r[2];
}

extern "C" void kernel_launch(void* const* d_in, const int* in_sizes, int n_in,
                              void* d_out, int out_size, void* d_ws, size_t ws_size,
                              hipStream_t stream) {
    const float* x     = (const float*)d_in[0];
    const float* wt    = (const float*)d_in[1];
    const float* off   = (const float*)d_in[2];
    const float* gamma = (const float*)d_in[3];
    const float* beta  = (const float*)d_in[4];

    float* out  = (float*)d_out;
    float*  bufA = (float*)d_ws;                             // 25.7 MB
    float*  bufB = bufA + (size_t)NPIX * 4;                  // 25.7 MB
    float4* tw   = (float4*)(bufB + (size_t)NPIX * 4);       // 7.2 MB
    int*    tc   = (int*)((char*)tw + (size_t)NTAPS * 16);   // 1.8 MB
    float*  stats = (float*)((char*)tc + (size_t)NTAPS * 4); // 7.7 KB
    // ws total ~= 60.5 MB

    zero_kernel<<<(LNUM * 192 + 255) / 256, 256, 0, stream>>>(stats, LNUM * 192);
    taps_kernel<<<NTAPS / 256, 256, 0, stream>>>(off, tw, tc);
    pack_kernel<<<NPIX / 256, 256, 0, stream>>>(x, (float4*)bufB);

    const float4* cur = (const float4*)bufB;
    const float* st_prev = nullptr;
    for (int it = 0; it < LNUM; ++it) {
        float4* dst = (float4*)((it & 1) ? bufB : bufA);
        float* st = stats + it * 192;
        if (it == 0)
            conv_fused<0><<<NBLK, 256, 0, stream>>>(cur, tw, tc, wt, nullptr,
                                                    gamma, beta, dst, st);
        else
            conv_fused<1><<<NBLK, 256, 0, stream>>>(cur, tw, tc, wt, st_prev,
                                                    gamma, beta, dst, st);
        cur = dst;
        st_prev = st;
    }
    norm_final<<<NPIX / 256, 256, 0, stream>>>(cur, out, st_prev, gamma, beta);
}